// Round 3
// baseline (248.556 us; speedup 1.0000x reference)
//
#include <hip/hip_runtime.h>

// QuantumRNNCell v5: fused, locality + pipeline + readlane-broadcast sim.
//
//   2048 blocks x 256 threads; each block owns 16 CONSECUTIVE rows (64 KB
//   contiguous hx read + 64 KB contiguous out write), processed as 4
//   iterations of 4 rows (one sim per wave per iteration).
//   Per iteration: issue 4 coalesced hx float4 loads -> run the sim (pure
//   VALU + cross-lane, ~1000 cy, hides the load latency) -> barrier ->
//   FMA + nontemporal stores. Double-buffered q6 LDS, single barrier/iter.
//
//   Sim: lane l holds amplitude of basis state l (wire w <-> bit 5-w).
//   All wave-uniform broadcasts use v_readlane (VALU/SGPR) instead of
//   ds_bpermute; qw sincos + broadcasts hoisted out of the row loop
//   (row-invariant). Data exchanges stay shfl_xor; CNOT ring = 1 shfl via
//   precomputed GF(2)-linear source lane; PauliZ = 6-stage WH butterfly.
//
// Fixed shape: B = 32768, H = 1024 (256 float4 per row).

#define NQ 6

typedef float floatx4 __attribute__((ext_vector_type(4)));

__device__ __forceinline__ float rl(float v, int lane) {
    return __int_as_float(__builtin_amdgcn_readlane(__float_as_int(v), lane));
}

__global__ __launch_bounds__(256, 4) void qrnn_fused_kernel(
    const float* __restrict__ x,     // (B, 6)
    const float* __restrict__ hx,    // (B, H)
    const float* __restrict__ qw,    // (3, 6)
    const float* __restrict__ fc_w,  // (H, 6)
    const float* __restrict__ fc_b,  // (H,)
    float* __restrict__ out)         // (B, H)
{
    const int tid = threadIdx.x;
    const int l   = tid & 63;        // lane = basis state
    const int wv  = tid >> 6;        // wave 0..3
    const int bid = blockIdx.x;

    __shared__ float q6s[2][4][6];   // double-buffered per-iteration q rows

    // ---- per-wave persistent state (reused for all 16 rows) ----
    // this lane's float4 output column: h4 = wv*64 + l
    const float4* w4 = (const float4*)fc_w;
    const int h4 = wv * 64 + l;
    const int wb = h4 * 6;
    const float4 a0 = w4[wb + 0], a1 = w4[wb + 1], a2 = w4[wb + 2];
    const float4 a3 = w4[wb + 3], a4 = w4[wb + 4], a5 = w4[wb + 5];
    const float4 bv = ((const float4*)fc_b)[h4];

    // variational-layer sincos, hoisted (row-invariant): lanes 6..23 <- qw
    float angq = (l >= 6 && l < 24) ? qw[l - 6] : 0.f;
    float saq, caq;
    __sincosf(angq * 0.5f, &saq, &caq);
    float cQ[3][6], sQ[3][6];        // 36 wave-uniform scalars -> SGPRs
    #pragma unroll
    for (int lay = 0; lay < 3; ++lay)
        #pragma unroll
        for (int q = 0; q < 6; ++q) {
            cQ[lay][q] = rl(caq, 6 + lay * 6 + q);
            sQ[lay][q] = rl(saq, 6 + lay * 6 + q);
        }

    // CNOT-ring composed permutation: new[l] = old[src]
    int src = l;
    #pragma unroll
    for (int q = 5; q >= 0; --q) {
        const int cb = 5 - q, tb = 5 - ((q + 1) % 6);
        src ^= ((src >> cb) & 1) << tb;
    }
    const int srcl = (l < 6) ? (32 >> l) : 0;   // WH result gather lane

    const float4* hx4 = (const float4*)hx;
    floatx4* out4 = (floatx4*)out;

    #pragma unroll 1
    for (int it = 0; it < 4; ++it) {
        const int r0 = bid * 16 + it * 4;       // first of this iter's 4 rows
        const int b  = r0 + wv;                 // this wave's sim row

        // x angles first so their wait doesn't drain the hv loads behind them
        const float angx = (l < 6) ? x[(size_t)b * NQ + l] : 0.f;

        // issue the 4 coalesced hx loads for this iteration
        float4 hv0 = hx4[(size_t)(r0 + 0) * 256 + h4];
        float4 hv1 = hx4[(size_t)(r0 + 1) * 256 + h4];
        float4 hv2 = hx4[(size_t)(r0 + 2) * 256 + h4];
        float4 hv3 = hx4[(size_t)(r0 + 3) * 256 + h4];

        // ---- sim (VALU + cross-lane only; hides hv latency) ----
        float sax, cax;
        __sincosf(angx * 0.5f, &sax, &cax);
        float cx[6], sx[6];
        #pragma unroll
        for (int i = 0; i < 6; ++i) { cx[i] = rl(cax, i); sx[i] = rl(sax, i); }

        float re = (l == 0) ? 1.f : 0.f;
        float im = 0.f;

        // encoding: RX(x[i]), RY(x[i+1]), RZ(x[i+2]) on wire i (bit 5-i)
        #pragma unroll
        for (int w = 0; w < 6; ++w) {
            const int m = 1 << (5 - w);
            const float sgn = (l & m) ? 1.f : -1.f;
            float pr = __shfl_xor(re, m), pi = __shfl_xor(im, m);
            float c = cx[w], s = sx[w];
            float nr = c * re + s * pi;
            float ni = c * im - s * pr;
            re = nr; im = ni;
            pr = __shfl_xor(re, m); pi = __shfl_xor(im, m);
            c = cx[(w + 1) % 6]; s = sx[(w + 1) % 6] * sgn;
            nr = c * re + s * pr;
            ni = c * im + s * pi;
            re = nr; im = ni;
            c = cx[(w + 2) % 6];
            const float sg = (l & m) ? -sx[(w + 2) % 6] : sx[(w + 2) % 6];
            nr = c * re + sg * im;
            ni = c * im - sg * re;
            re = nr; im = ni;
        }

        // variational layers: 6x RY(qw[lay][q]) then CNOT ring
        #pragma unroll
        for (int lay = 0; lay < 3; ++lay) {
            #pragma unroll
            for (int q = 0; q < 6; ++q) {
                const int m = 1 << (5 - q);
                const float c = cQ[lay][q];
                const float s = sQ[lay][q];
                const float sg = (l & m) ? s : -s;
                const float pr = __shfl_xor(re, m), pi = __shfl_xor(im, m);
                const float nr = c * re + sg * pr;
                const float ni = c * im + sg * pi;
                re = nr; im = ni;
            }
            re = __shfl(re, src);
            im = __shfl(im, src);
        }

        // probabilities -> 6-stage Walsh-Hadamard; q[j] lands at lane 32>>j
        float p = re * re + im * im;
        #pragma unroll
        for (int k = 0; k < 6; ++k) {
            const int m = 1 << k;
            const float t = __shfl_xor(p, m);
            p = (l & m) ? (t - p) : (t + p);
        }
        const float v = __shfl(p, srcl);
        if (l < 6) q6s[it & 1][wv][l] = v;
        __syncthreads();

        // ---- epilogue: out = hx + q6 @ fc_w^T + fc_b for the 4 rows ----
        #pragma unroll
        for (int r = 0; r < 4; ++r) {
            const float* qb = q6s[it & 1][r];
            const float q0 = qb[0], q1 = qb[1], q2 = qb[2];
            const float q3 = qb[3], q4 = qb[4], q5 = qb[5];
            const float4 hvk = (r == 0) ? hv0 : (r == 1) ? hv1 : (r == 2) ? hv2 : hv3;
            floatx4 res;
            res.x = hvk.x + bv.x + q0*a0.x + q1*a0.y + q2*a0.z + q3*a0.w + q4*a1.x + q5*a1.y;
            res.y = hvk.y + bv.y + q0*a1.z + q1*a1.w + q2*a2.x + q3*a2.y + q4*a2.z + q5*a2.w;
            res.z = hvk.z + bv.z + q0*a3.x + q1*a3.y + q2*a3.z + q3*a3.w + q4*a4.x + q5*a4.y;
            res.w = hvk.w + bv.w + q0*a4.z + q1*a4.w + q2*a5.x + q3*a5.y + q4*a5.z + q5*a5.w;
            __builtin_nontemporal_store(res, &out4[(size_t)(r0 + r) * 256 + h4]);
        }
    }
}

extern "C" void kernel_launch(void* const* d_in, const int* in_sizes, int n_in,
                              void* d_out, int out_size, void* d_ws, size_t ws_size,
                              hipStream_t stream) {
    const float* x    = (const float*)d_in[0];   // (B, 6)
    const float* hx   = (const float*)d_in[1];   // (B, H)
    const float* qw   = (const float*)d_in[2];   // (3, 6)
    const float* fc_w = (const float*)d_in[3];   // (H, 6)
    const float* fc_b = (const float*)d_in[4];   // (H,)
    float* out = (float*)d_out;

    const int B = in_sizes[0] / NQ;              // 32768
    // H fixed at 1024 (kernel hardcodes 256 float4 per row)

    // 16 consecutive rows per block; 2048 blocks = 8 resident per CU
    qrnn_fused_kernel<<<B / 16, 256, 0, stream>>>(x, hx, qw, fc_w, fc_b, out);
}